// Round 1
// 6460.056 us; speedup vs baseline: 2.0285x; 2.0285x over previous
//
#include <hip/hip_runtime.h>
#include <hip/hip_bf16.h>
#include <cstdint>
#include <cstddef>

// Problem constants
#define VOCAB 32000
#define HID   1024
#define EMB   512
#define RANK  64
#define BATCH 16
#define SEQ   256
#define MROWS 4096      // SEQ*BATCH, row m = t*16 + b (time-major)
#define N1    1088      // HID + RANK
#define N1PAD 1152      // padded to 9*128

typedef __attribute__((ext_vector_type(8))) short short8;
typedef __attribute__((ext_vector_type(4))) float f32x4;
typedef unsigned long long u64;

union S8 { u64 q[2]; short8 v; };

#define MFMA(a, b, c) __builtin_amdgcn_mfma_f32_16x16x32_bf16((a), (b), (c), 0, 0, 0)

__device__ __forceinline__ float bf2f(unsigned short u) {
  unsigned int x = ((unsigned int)u) << 16;
  return __builtin_bit_cast(float, x);
}
__device__ __forceinline__ unsigned short f2bf(float f) {
  unsigned int x = __builtin_bit_cast(unsigned int, f);
  unsigned int r = (x + 0x7fffu + ((x >> 16) & 1u)) >> 16;
  return (unsigned short)r;
}
__device__ __forceinline__ void gl_lds16(const void* g, void* l) {
  __builtin_amdgcn_global_load_lds(
      (const __attribute__((address_space(1))) unsigned int*)g,
      (__attribute__((address_space(3))) unsigned int*)l, 16, 0, 0);
}

// ---------------------------------------------------------------------------
// prep: zero H2 buf0 (65536 B = 16384 floats), barrier counters, UBt pad rows
// ---------------------------------------------------------------------------
__global__ void prep_misc(float* Hbuf0, unsigned int* bars, unsigned short* ubt_pad) {
  int i = blockIdx.x * blockDim.x + threadIdx.x;
  if (i < BATCH * HID) Hbuf0[i] = 0.f;
  if (i < 1024) bars[i] = 0u;
  if (i < 64 * EMB) ubt_pad[i] = 0;
}

// ---------------------------------------------------------------------------
// fp32 -> bf16 bulk convert (n multiple of 1024; each thread does 4)
// ---------------------------------------------------------------------------
__global__ void conv_f2b(const float* __restrict__ src, unsigned short* __restrict__ dst) {
  int i = (blockIdx.x * blockDim.x + threadIdx.x) * 4;
  float4 v = *(const float4*)(src + i);
  ushort4 o;
  o.x = f2bf(v.x); o.y = f2bf(v.y); o.z = f2bf(v.z); o.w = f2bf(v.w);
  *(ushort4*)(dst + i) = o;
}

// ---------------------------------------------------------------------------
// 32x32 tiled transpose + convert: src fp32 [R,C] -> dst bf16 [C,R]
// ---------------------------------------------------------------------------
__global__ void transpose_f2b(const float* __restrict__ src,
                              unsigned short* __restrict__ dst, int R, int C) {
  __shared__ float t[32][33];
  int c0 = blockIdx.x * 32, r0 = blockIdx.y * 32;
  int tx = threadIdx.x & 31, ty = threadIdx.x >> 5;  // 256 thr: ty 0..7
  for (int i = ty; i < 32; i += 8) t[i][tx] = src[(size_t)(r0 + i) * C + c0 + tx];
  __syncthreads();
  for (int i = ty; i < 32; i += 8)
    dst[(size_t)(c0 + i) * R + r0 + tx] = f2bf(t[tx][i]);
}

// ---------------------------------------------------------------------------
// MFMA GEMM: C = A[M,K] * Bt[N,K]^T (+bias fp32), 128x128 tile, BK=32.
// MODE 0: A rows gathered from emb_bf16 via tok; fp32 out, col<N guard,
//         bias only for col<HID.
// MODE 1: fp32 out to d_out with row remap (m=t*16+b -> orow=b*256+t)
// ---------------------------------------------------------------------------
template <int MODE>
__global__ __launch_bounds__(256) void gemm_bt(
    const unsigned short* __restrict__ Abase, const int* __restrict__ tok,
    const unsigned short* __restrict__ Bt, const float* __restrict__ bias,
    float* __restrict__ outf, int M, int N, int K, int ntiles) {
  __shared__ __align__(16) unsigned short As[128 * 32];
  __shared__ __align__(16) unsigned short Bs[128 * 32];
  int bn = blockIdx.x % ntiles, bm = blockIdx.x / ntiles;
  int tid = threadIdx.x, lane = tid & 63, w = tid >> 6;
  int wr = w >> 1, wc = w & 1;
  int fr = lane & 15, kq = lane >> 4;

  f32x4 zero = {0.f, 0.f, 0.f, 0.f};
  f32x4 acc[4][4];
#pragma unroll
  for (int i = 0; i < 4; ++i)
#pragma unroll
    for (int j = 0; j < 4; ++j) acc[i][j] = zero;

  int kIters = K >> 5;
  for (int kt = 0; kt < kIters; ++kt) {
    __syncthreads();
    int kb = kt << 5;
#pragma unroll
    for (int ii = 0; ii < 2; ++ii) {
      int e = w * 1024 + ii * 512 + lane * 8;  // element index in 128x32 tile
      int row = e >> 5, col = e & 31;
      {  // A tile
        int gm = bm * 128 + row;
        const unsigned short* gp;
        if (MODE == 0)
          gp = Abase + (size_t)tok[((gm & 15) << 8) + (gm >> 4)] * K + (kb + col);
        else
          gp = Abase + (size_t)gm * K + kb + col;
        gl_lds16(gp, &As[w * 1024 + ii * 512]);
      }
      {  // B tile (Bt is [N,K] row-major bf16)
        int gn = bn * 128 + row;
        const unsigned short* gp = Bt + (size_t)gn * K + kb + col;
        gl_lds16(gp, &Bs[w * 1024 + ii * 512]);
      }
    }
    __builtin_amdgcn_s_waitcnt(0);
    __syncthreads();

    short8 af[4], bfr[4];
#pragma unroll
    for (int mi = 0; mi < 4; ++mi)
      af[mi] = *(const short8*)&As[((wr << 6) + (mi << 4) + fr) * 32 + (kq << 3)];
#pragma unroll
    for (int ni = 0; ni < 4; ++ni)
      bfr[ni] = *(const short8*)&Bs[((wc << 6) + (ni << 4) + fr) * 32 + (kq << 3)];
#pragma unroll
    for (int mi = 0; mi < 4; ++mi)
#pragma unroll
      for (int ni = 0; ni < 4; ++ni)
        acc[mi][ni] = MFMA(af[mi], bfr[ni], acc[mi][ni]);
  }

  // epilogue: C/D layout col=lane&15, row=(lane>>4)*4+reg  [m89]
  int rbase = bm * 128 + (wr << 6);
  int cbase = bn * 128 + (wc << 6);
#pragma unroll
  for (int mi = 0; mi < 4; ++mi)
#pragma unroll
    for (int ni = 0; ni < 4; ++ni)
#pragma unroll
      for (int r = 0; r < 4; ++r) {
        int row = rbase + (mi << 4) + (kq << 2) + r;
        int col = cbase + (ni << 4) + fr;
        float v = acc[mi][ni][r];
        if (MODE == 0) {
          if (col < N) {
            float bv = (col < HID) ? bias[col] : 0.f;
            outf[(size_t)row * N + col] = v + bv;
          }
        } else {
          float o = v + bias[col];
          int orow = ((row & 15) << 8) + (row >> 4);  // b*256 + t
          outf[(size_t)orow * VOCAB + col] = o;
        }
      }
}

// ---------------------------------------------------------------------------
// Recurrent scan, v2: 16 blocks x 256 threads. Block p owns h-cols [64p,64p+64)
// for ALL 16 samples (batch = MFMA M dimension = 16).
//
// Per step, per block (all MFMA 16x16x32 bf16):
//   z[16s][64j]  = H(hi+lo) @ V[:,slice]      (V-slice bf16 in LDS, swizzled)
//   a[16s][64r]  = H(hi+lo) @ A               (A^T bf16 streamed from L2)
//   g[s][r]      = a * (x@B)  -> LDS hi/lo
//   z           += g(hi+lo) @ C[slice,:]^T    (C-slice bf16 in LDS)
//   h_new        = tanh(z + u_cat slice); store bf16 hi/lo to H2[nxt] (agent)
//   ONE grid barrier (16 blocks, tid0 spins, monotonic counter)
//
// H exchanged as hi/lo bf16 pair => recurrent state keeps ~fp32 precision.
// Cross-block H reads: relaxed agent-scope 8B atomic loads (cache-bypass).
// LDS: Vt 128K + Cs 8K + g2 4K = 140 KB (1 block/CU).
// ---------------------------------------------------------------------------
__global__ __launch_bounds__(256) void scan_kernel(
    const float* __restrict__ u_cat,            // [4096][1088] fp32 = [xU+d | xB]
    const unsigned short* __restrict__ ATb,     // [64][1024] bf16 = A^T
    const float* __restrict__ V,                // [1024][1024] fp32
    const float* __restrict__ Cm,               // [1024][64] fp32
    unsigned short* __restrict__ H2,            // [2 buf][2 comp][16][1024] bf16
    unsigned int* __restrict__ bars,            // monotonic counter (bars[0])
    unsigned short* __restrict__ hseq) {        // [4096][1024] bf16
  __shared__ __align__(16) unsigned short Vt[64 * 1024];  // Vt[n][k]=V[k][64p+n], swz
  __shared__ __align__(16) unsigned short Cs[64 * 64];    // Cs[j][r]=C[64p+j][r], swz
  __shared__ __align__(16) unsigned short g2[2 * 16 * 64];// [comp][s][r], swz

  const int p = blockIdx.x;
  const int tid = threadIdx.x, lane = tid & 63, w = tid >> 6;
  const int fr = lane & 15, kq = lane >> 4;

  // ---- one-time LDS fills ----
  {  // V slice: wave-coalesced 256B rows of V, transposed into Vt
    const int n = lane;
    const float* vcol = V + (size_t)p * 64 + n;
    for (int k0 = w * 256; k0 < w * 256 + 256; k0 += 8) {
      short8 tv;
#pragma unroll
      for (int j = 0; j < 8; ++j) tv[j] = (short)f2bf(vcol[(size_t)(k0 + j) * HID]);
      int byt = ((n * 1024 + k0) * 2) ^ ((n & 7) << 4);   // XOR applied last
      *(short8*)((char*)Vt + byt) = tv;
    }
  }
  {  // C slice
    int j = tid >> 2, rq = (tid & 3) << 4;
    const float* crow = Cm + (size_t)(p * 64 + j) * RANK + rq;
    short8 c0, c1;
#pragma unroll
    for (int i = 0; i < 8; ++i) {
      c0[i] = (short)f2bf(crow[i]);
      c1[i] = (short)f2bf(crow[8 + i]);
    }
    *(short8*)((char*)Cs + (((j * 64 + rq) * 2) ^ ((j & 7) << 4))) = c0;
    *(short8*)((char*)Cs + (((j * 64 + rq + 8) * 2) ^ ((j & 7) << 4))) = c1;
  }
  __syncthreads();

  // per-thread constant offsets
  const int hoff = fr * 1024 + kq * 8;                  // ushorts, within comp plane
  const int vbase = (w * 16 + fr) * 2048 + kq * 16;     // bytes, pre-swizzle
  const int vsw = (fr & 7) << 4;
  const unsigned short* ATrow = ATb + (size_t)(w * 16 + fr) * 1024 + kq * 8;
  const int jg = p * 64 + w * 16 + fr;                  // global h column

  for (int t = 0; t < SEQ; ++t) {
    const int cur = t & 1, nxt = cur ^ 1;
    const unsigned short* Hc0 = H2 + cur * 32768 + hoff;          // hi plane
    const unsigned short* Hc1 = Hc0 + 16384;                      // lo plane

    // prefetch u_cat terms (static data, hides under k-loop)
    float ucz[4], bp[4];
#pragma unroll
    for (int rg = 0; rg < 4; ++rg) {
      int s = kq * 4 + rg;
      const float* ur = u_cat + (size_t)(t * 16 + s) * N1;
      ucz[rg] = ur[jg];                   // (x@U + d) slice column jg
      bp[rg] = ur[HID + w * 16 + fr];     // (x@B) at rank r = w*16+fr
    }

    // K-loop: z (V-part) and a, hi/lo split => 4 independent MFMA chains
    f32x4 zh = {0.f, 0.f, 0.f, 0.f}, zl = zh, ah = zh, al = zh;
#pragma unroll 4
    for (int kt = 0; kt < 32; ++kt) {
      S8 hf, lf;
      hf.q[0] = __hip_atomic_load((const u64*)(Hc0 + kt * 32),
                                  __ATOMIC_RELAXED, __HIP_MEMORY_SCOPE_AGENT);
      hf.q[1] = __hip_atomic_load((const u64*)(Hc0 + kt * 32 + 4),
                                  __ATOMIC_RELAXED, __HIP_MEMORY_SCOPE_AGENT);
      lf.q[0] = __hip_atomic_load((const u64*)(Hc1 + kt * 32),
                                  __ATOMIC_RELAXED, __HIP_MEMORY_SCOPE_AGENT);
      lf.q[1] = __hip_atomic_load((const u64*)(Hc1 + kt * 32 + 4),
                                  __ATOMIC_RELAXED, __HIP_MEMORY_SCOPE_AGENT);
      short8 vf = *(const short8*)((const char*)Vt + ((vbase + kt * 64) ^ vsw));
      short8 af = *(const short8*)(ATrow + kt * 32);
      zh = MFMA(hf.v, vf, zh);
      zl = MFMA(lf.v, vf, zl);
      ah = MFMA(hf.v, af, ah);
      al = MFMA(lf.v, af, al);
    }

    // g = (h@A) * (x@B) -> LDS, hi/lo bf16, A-fragment layout
#pragma unroll
    for (int rg = 0; rg < 4; ++rg) {
      int s = kq * 4 + rg;
      float gval = (ah[rg] + al[rg]) * bp[rg];
      unsigned short ghi = f2bf(gval);
      unsigned short glo = f2bf(gval - bf2f(ghi));
      int base = (s * 64 + w * 16 + fr) * 2;
      int sw = (s & 7) << 4;
      *(unsigned short*)((char*)g2 + (base ^ sw)) = ghi;
      *(unsigned short*)((char*)g2 + ((base + 2048) ^ sw)) = glo;
    }
    __syncthreads();

    // cp: z += g @ C_slice^T  (K = 64, 2 k-steps, hi/lo)
#pragma unroll
    for (int kt2 = 0; kt2 < 2; ++kt2) {
      int k = kt2 * 32 + kq * 8;
      int gsw = (fr & 7) << 4;
      short8 gh = *(const short8*)((const char*)g2 + (((fr * 64 + k) * 2) ^ gsw));
      short8 gl = *(const short8*)((const char*)g2 + (((fr * 64 + k) * 2 + 2048) ^ gsw));
      short8 cf = *(const short8*)((const char*)Cs +
                                   ((((w * 16 + fr) * 64 + k) * 2) ^ gsw));
      zh = MFMA(gh, cf, zh);
      zl = MFMA(gl, cf, zl);
    }

    // epilogue: h_new = tanh(z + ucz); store hseq + H2[nxt] (hi/lo, agent scope)
    unsigned short* Hn = H2 + nxt * 32768;
#pragma unroll
    for (int rg = 0; rg < 4; ++rg) {
      int s = kq * 4 + rg;
      float z = zh[rg] + zl[rg] + ucz[rg];
      float h = tanhf(z);
      unsigned short hi = f2bf(h);
      hseq[(size_t)(t * 16 + s) * HID + jg] = hi;
      unsigned short lo = f2bf(h - bf2f(hi));
      __hip_atomic_store(Hn + s * 1024 + jg, hi, __ATOMIC_RELAXED,
                         __HIP_MEMORY_SCOPE_AGENT);
      __hip_atomic_store(Hn + 16384 + s * 1024 + jg, lo, __ATOMIC_RELAXED,
                         __HIP_MEMORY_SCOPE_AGENT);
    }

    // single grid barrier: syncthreads drains all waves' stores, tid0 releases
    __syncthreads();
    if (tid == 0) {
      __threadfence();
      __hip_atomic_fetch_add(bars, 1u, __ATOMIC_RELEASE, __HIP_MEMORY_SCOPE_AGENT);
      unsigned int tg = (unsigned int)(t + 1) * 16u;
      while (__hip_atomic_load(bars, __ATOMIC_RELAXED, __HIP_MEMORY_SCOPE_AGENT) < tg)
        __builtin_amdgcn_s_sleep(1);
    }
    __syncthreads();
    __builtin_amdgcn_fence(__ATOMIC_ACQUIRE, "agent");
  }
}

// ---------------------------------------------------------------------------
extern "C" void kernel_launch(void* const* d_in, const int* in_sizes, int n_in,
                              void* d_out, int out_size, void* d_ws, size_t ws_size,
                              hipStream_t stream) {
  const int*   inp  = (const int*)d_in[0];
  const float* emb  = (const float*)d_in[1];   // [32000][512]
  const float* Amat = (const float*)d_in[2];   // [1024][64]
  const float* Bmat = (const float*)d_in[3];   // [512][64]
  const float* Cmat = (const float*)d_in[4];   // [1024][64]
  const float* Umat = (const float*)d_in[5];   // [512][1024]
  const float* Vmat = (const float*)d_in[6];   // [1024][1024]
  const float* dvec = (const float*)d_in[7];   // [1024]
  const float* Wdec = (const float*)d_in[8];   // [1024][32000]
  const float* bdec = (const float*)d_in[9];   // [32000]
  float* out = (float*)d_out;

  char* ws = (char*)d_ws;
  size_t off = 0;
  auto alloc = [&](size_t bytes) -> void* {
    void* pp = ws + off;
    off = (off + bytes + 255) & ~(size_t)255;
    return pp;
  };
  // persistent region
  unsigned short* hseq = (unsigned short*)alloc((size_t)MROWS * HID * 2);   // 8.39 MB
  unsigned short* H2   = (unsigned short*)alloc((size_t)2 * 2 * BATCH * HID * 2); // 128 KB
  unsigned short* ATb  = (unsigned short*)alloc((size_t)RANK * HID * 2);    // 128 KB
  unsigned int* bars   = (unsigned int*)alloc(1024 * 4);
  // union region: {emb_bf16, UBt, u_cat} (phases 1-3) aliased with WdT (4-5)
  size_t union_off = off;
  unsigned short* emb_b = (unsigned short*)alloc((size_t)VOCAB * EMB * 2);  // 32.8 MB
  unsigned short* UBt   = (unsigned short*)alloc((size_t)N1PAD * EMB * 2);  // 1.18 MB
  float* u_cat = (float*)alloc((size_t)MROWS * N1 * 4);                     // 17.8 MB
  unsigned short* WdT = (unsigned short*)(ws + union_off);                  // 65.5 MB alias

  // phase 0: prep + conversions (H2 buf0 = 65536 B = 16384 floats zeroed)
  prep_misc<<<128, 256, 0, stream>>>((float*)H2, bars, UBt + (size_t)N1 * EMB);
  conv_f2b<<<(VOCAB * EMB) / 1024, 256, 0, stream>>>(emb, emb_b);
  // UBt rows 0..1023 = U^T, rows 1024..1087 = B^T, rows 1088..1151 = 0
  transpose_f2b<<<dim3(HID / 32, EMB / 32), 256, 0, stream>>>(Umat, UBt, EMB, HID);
  transpose_f2b<<<dim3(RANK / 32, EMB / 32), 256, 0, stream>>>(
      Bmat, UBt + (size_t)HID * EMB, EMB, RANK);
  // A^T bf16 [64][1024] for the scan's rank projection
  transpose_f2b<<<dim3(RANK / 32, HID / 32), 256, 0, stream>>>(Amat, ATb, HID, RANK);

  // phase 1: u_cat = gather(embedding, inp) @ [U | B] + [d | 0]
  gemm_bt<0><<<9 * (MROWS / 128), 256, 0, stream>>>(emb_b, inp, UBt, dvec, u_cat,
                                                    MROWS, N1, EMB, 9);
  // phase 2: recurrent scan (16 blocks, MFMA, 1 barrier/step)
  scan_kernel<<<16, 256, 0, stream>>>(u_cat, ATb, Vmat, Cmat, H2, bars, hseq);
  // phase 3: W_dec transpose (aliases dead emb_b/UBt/u_cat region)
  transpose_f2b<<<dim3(VOCAB / 32, HID / 32), 256, 0, stream>>>(Wdec, WdT, HID, VOCAB);
  // phase 4: logits = hseq @ W_dec + b_dec, remapped to [B,S,V]
  gemm_bt<1><<<250 * (MROWS / 128), 256, 0, stream>>>(hseq, nullptr, WdT, bdec, out,
                                                      MROWS, VOCAB, HID, 250);
}

// Round 2
// 5997.690 us; speedup vs baseline: 2.1849x; 1.0771x over previous
//
#include <hip/hip_runtime.h>
#include <hip/hip_bf16.h>
#include <cstdint>
#include <cstddef>

// Problem constants
#define VOCAB 32000
#define HID   1024
#define EMB   512
#define RANK  64
#define BATCH 16
#define SEQ   256
#define MROWS 4096      // SEQ*BATCH, row m = t*16 + b (time-major)
#define N1    1088      // HID + RANK
#define N1PAD 1152      // padded to 9*128

typedef __attribute__((ext_vector_type(8))) short short8;
typedef __attribute__((ext_vector_type(4))) float f32x4;
typedef unsigned long long u64;

union S8 { u64 q[2]; short8 v; };

#define MFMA(a, b, c) __builtin_amdgcn_mfma_f32_16x16x32_bf16((a), (b), (c), 0, 0, 0)

__device__ __forceinline__ float bf2f(unsigned short u) {
  unsigned int x = ((unsigned int)u) << 16;
  return __builtin_bit_cast(float, x);
}
__device__ __forceinline__ unsigned short f2bf(float f) {
  unsigned int x = __builtin_bit_cast(unsigned int, f);
  unsigned int r = (x + 0x7fffu + ((x >> 16) & 1u)) >> 16;
  return (unsigned short)r;
}
__device__ __forceinline__ void gl_lds16(const void* g, void* l) {
  __builtin_amdgcn_global_load_lds(
      (const __attribute__((address_space(1))) unsigned int*)g,
      (__attribute__((address_space(3))) unsigned int*)l, 16, 0, 0);
}

// ---------------------------------------------------------------------------
// prep: zero H2 buf0 (65536 B = 16384 floats), barrier counters, UBt pad rows
// ---------------------------------------------------------------------------
__global__ void prep_misc(float* Hbuf0, unsigned int* bars, unsigned short* ubt_pad) {
  int i = blockIdx.x * blockDim.x + threadIdx.x;
  if (i < BATCH * HID) Hbuf0[i] = 0.f;
  if (i < 1024) bars[i] = 0u;
  if (i < 64 * EMB) ubt_pad[i] = 0;
}

// ---------------------------------------------------------------------------
// fp32 -> bf16 bulk convert (n multiple of 1024; each thread does 4)
// ---------------------------------------------------------------------------
__global__ void conv_f2b(const float* __restrict__ src, unsigned short* __restrict__ dst) {
  int i = (blockIdx.x * blockDim.x + threadIdx.x) * 4;
  float4 v = *(const float4*)(src + i);
  ushort4 o;
  o.x = f2bf(v.x); o.y = f2bf(v.y); o.z = f2bf(v.z); o.w = f2bf(v.w);
  *(ushort4*)(dst + i) = o;
}

// ---------------------------------------------------------------------------
// 32x32 tiled transpose + convert: src fp32 [R,C] -> dst bf16 [C,R]
// ---------------------------------------------------------------------------
__global__ void transpose_f2b(const float* __restrict__ src,
                              unsigned short* __restrict__ dst, int R, int C) {
  __shared__ float t[32][33];
  int c0 = blockIdx.x * 32, r0 = blockIdx.y * 32;
  int tx = threadIdx.x & 31, ty = threadIdx.x >> 5;  // 256 thr: ty 0..7
  for (int i = ty; i < 32; i += 8) t[i][tx] = src[(size_t)(r0 + i) * C + c0 + tx];
  __syncthreads();
  for (int i = ty; i < 32; i += 8)
    dst[(size_t)(c0 + i) * R + r0 + tx] = f2bf(t[tx][i]);
}

// ---------------------------------------------------------------------------
// MFMA GEMM: C = A[M,K] * Bt[N,K]^T (+bias fp32), 128x128 tile, BK=32.
// MODE 0: A rows gathered from emb_bf16 via tok; fp32 out, col<N guard,
//         bias only for col<HID.
// MODE 1: fp32 out to d_out with row remap (m=t*16+b -> orow=b*256+t)
// ---------------------------------------------------------------------------
template <int MODE>
__global__ __launch_bounds__(256) void gemm_bt(
    const unsigned short* __restrict__ Abase, const int* __restrict__ tok,
    const unsigned short* __restrict__ Bt, const float* __restrict__ bias,
    float* __restrict__ outf, int M, int N, int K, int ntiles) {
  __shared__ __align__(16) unsigned short As[128 * 32];
  __shared__ __align__(16) unsigned short Bs[128 * 32];
  int bn = blockIdx.x % ntiles, bm = blockIdx.x / ntiles;
  int tid = threadIdx.x, lane = tid & 63, w = tid >> 6;
  int wr = w >> 1, wc = w & 1;
  int fr = lane & 15, kq = lane >> 4;

  f32x4 zero = {0.f, 0.f, 0.f, 0.f};
  f32x4 acc[4][4];
#pragma unroll
  for (int i = 0; i < 4; ++i)
#pragma unroll
    for (int j = 0; j < 4; ++j) acc[i][j] = zero;

  int kIters = K >> 5;
  for (int kt = 0; kt < kIters; ++kt) {
    __syncthreads();
    int kb = kt << 5;
#pragma unroll
    for (int ii = 0; ii < 2; ++ii) {
      int e = w * 1024 + ii * 512 + lane * 8;  // element index in 128x32 tile
      int row = e >> 5, col = e & 31;
      {  // A tile
        int gm = bm * 128 + row;
        const unsigned short* gp;
        if (MODE == 0)
          gp = Abase + (size_t)tok[((gm & 15) << 8) + (gm >> 4)] * K + (kb + col);
        else
          gp = Abase + (size_t)gm * K + kb + col;
        gl_lds16(gp, &As[w * 1024 + ii * 512]);
      }
      {  // B tile (Bt is [N,K] row-major bf16)
        int gn = bn * 128 + row;
        const unsigned short* gp = Bt + (size_t)gn * K + kb + col;
        gl_lds16(gp, &Bs[w * 1024 + ii * 512]);
      }
    }
    __builtin_amdgcn_s_waitcnt(0);
    __syncthreads();

    short8 af[4], bfr[4];
#pragma unroll
    for (int mi = 0; mi < 4; ++mi)
      af[mi] = *(const short8*)&As[((wr << 6) + (mi << 4) + fr) * 32 + (kq << 3)];
#pragma unroll
    for (int ni = 0; ni < 4; ++ni)
      bfr[ni] = *(const short8*)&Bs[((wc << 6) + (ni << 4) + fr) * 32 + (kq << 3)];
#pragma unroll
    for (int mi = 0; mi < 4; ++mi)
#pragma unroll
      for (int ni = 0; ni < 4; ++ni)
        acc[mi][ni] = MFMA(af[mi], bfr[ni], acc[mi][ni]);
  }

  // epilogue: C/D layout col=lane&15, row=(lane>>4)*4+reg  [m89]
  int rbase = bm * 128 + (wr << 6);
  int cbase = bn * 128 + (wc << 6);
#pragma unroll
  for (int mi = 0; mi < 4; ++mi)
#pragma unroll
    for (int ni = 0; ni < 4; ++ni)
#pragma unroll
      for (int r = 0; r < 4; ++r) {
        int row = rbase + (mi << 4) + (kq << 2) + r;
        int col = cbase + (ni << 4) + fr;
        float v = acc[mi][ni][r];
        if (MODE == 0) {
          if (col < N) {
            float bv = (col < HID) ? bias[col] : 0.f;
            outf[(size_t)row * N + col] = v + bv;
          }
        } else {
          float o = v + bias[col];
          int orow = ((row & 15) << 8) + (row >> 4);  // b*256 + t
          outf[(size_t)orow * VOCAB + col] = o;
        }
      }
}

// ---------------------------------------------------------------------------
// Recurrent scan, v3: 16 blocks x 256 threads. Block p owns h-cols [64p,64p+64)
// for ALL 16 samples (batch = MFMA M dimension = 16).
//
// v3 change vs v2: NO agent-scope fences in the step loop. __threadfence()
// emitted buffer_wbl2 (full-L2 writeback) and the acquire fence emitted
// buffer_inv (full-L2 invalidate) EVERY STEP -> microseconds of cacheop per
// step + evicted the read-only working set (ATb/u_cat), causing 80 MB of HBM
// refetch. All cross-block data (H2, bars) travels via agent-scope RELAXED
// atomics that bypass L2 and complete at the LLC; __syncthreads() itself
// drains each wave's vmem (s_waitcnt vmcnt(0) before s_barrier), so by the
// time tid0 issues the barrier fetch-add, all H stores are at the coherence
// point. No wbl2/inv needed.
// ---------------------------------------------------------------------------
__global__ __launch_bounds__(256) void scan_kernel(
    const float* __restrict__ u_cat,            // [4096][1088] fp32 = [xU+d | xB]
    const unsigned short* __restrict__ ATb,     // [64][1024] bf16 = A^T
    const float* __restrict__ V,                // [1024][1024] fp32
    const float* __restrict__ Cm,               // [1024][64] fp32
    unsigned short* __restrict__ H2,            // [2 buf][2 comp][16][1024] bf16
    unsigned int* __restrict__ bars,            // monotonic counter (bars[0])
    unsigned short* __restrict__ hseq) {        // [4096][1024] bf16
  __shared__ __align__(16) unsigned short Vt[64 * 1024];  // Vt[n][k]=V[k][64p+n], swz
  __shared__ __align__(16) unsigned short Cs[64 * 64];    // Cs[j][r]=C[64p+j][r], swz
  __shared__ __align__(16) unsigned short g2[2 * 16 * 64];// [comp][s][r], swz

  const int p = blockIdx.x;
  const int tid = threadIdx.x, lane = tid & 63, w = tid >> 6;
  const int fr = lane & 15, kq = lane >> 4;

  // ---- one-time LDS fills ----
  {  // V slice: wave-coalesced 256B rows of V, transposed into Vt
    const int n = lane;
    const float* vcol = V + (size_t)p * 64 + n;
    for (int k0 = w * 256; k0 < w * 256 + 256; k0 += 8) {
      short8 tv;
#pragma unroll
      for (int j = 0; j < 8; ++j) tv[j] = (short)f2bf(vcol[(size_t)(k0 + j) * HID]);
      int byt = ((n * 1024 + k0) * 2) ^ ((n & 7) << 4);   // XOR applied last
      *(short8*)((char*)Vt + byt) = tv;
    }
  }
  {  // C slice
    int j = tid >> 2, rq = (tid & 3) << 4;
    const float* crow = Cm + (size_t)(p * 64 + j) * RANK + rq;
    short8 c0, c1;
#pragma unroll
    for (int i = 0; i < 8; ++i) {
      c0[i] = (short)f2bf(crow[i]);
      c1[i] = (short)f2bf(crow[8 + i]);
    }
    *(short8*)((char*)Cs + (((j * 64 + rq) * 2) ^ ((j & 7) << 4))) = c0;
    *(short8*)((char*)Cs + (((j * 64 + rq + 8) * 2) ^ ((j & 7) << 4))) = c1;
  }
  __syncthreads();

  // per-thread constant offsets
  const int hoff = fr * 1024 + kq * 8;                  // ushorts, within comp plane
  const int vbase = (w * 16 + fr) * 2048 + kq * 16;     // bytes, pre-swizzle
  const int vsw = (fr & 7) << 4;
  const unsigned short* ATrow = ATb + (size_t)(w * 16 + fr) * 1024 + kq * 8;
  const int jg = p * 64 + w * 16 + fr;                  // global h column

  // u_cat prefetch for step 0 (ucz = (x@U+d) col jg; bp = (x@B) rank w*16+fr)
  float ucz[4], bp[4];
#pragma unroll
  for (int rg = 0; rg < 4; ++rg) {
    int s = kq * 4 + rg;
    const float* ur = u_cat + (size_t)(0 * 16 + s) * N1;
    ucz[rg] = ur[jg];
    bp[rg] = ur[HID + w * 16 + fr];
  }

  for (int t = 0; t < SEQ; ++t) {
    const int cur = t & 1, nxt = cur ^ 1;
    const unsigned short* Hc0 = H2 + cur * 32768 + hoff;          // hi plane
    const unsigned short* Hc1 = Hc0 + 16384;                      // lo plane

    // K-loop: z (V-part) and a, hi/lo split => 4 independent MFMA chains
    f32x4 zh = {0.f, 0.f, 0.f, 0.f}, zl = zh, ah = zh, al = zh;
#pragma unroll 8
    for (int kt = 0; kt < 32; ++kt) {
      S8 hf, lf;
      hf.q[0] = __hip_atomic_load((const u64*)(Hc0 + kt * 32),
                                  __ATOMIC_RELAXED, __HIP_MEMORY_SCOPE_AGENT);
      hf.q[1] = __hip_atomic_load((const u64*)(Hc0 + kt * 32 + 4),
                                  __ATOMIC_RELAXED, __HIP_MEMORY_SCOPE_AGENT);
      lf.q[0] = __hip_atomic_load((const u64*)(Hc1 + kt * 32),
                                  __ATOMIC_RELAXED, __HIP_MEMORY_SCOPE_AGENT);
      lf.q[1] = __hip_atomic_load((const u64*)(Hc1 + kt * 32 + 4),
                                  __ATOMIC_RELAXED, __HIP_MEMORY_SCOPE_AGENT);
      short8 vf = *(const short8*)((const char*)Vt + ((vbase + kt * 64) ^ vsw));
      short8 af = *(const short8*)(ATrow + kt * 32);
      zh = MFMA(hf.v, vf, zh);
      zl = MFMA(lf.v, vf, zl);
      ah = MFMA(hf.v, af, ah);
      al = MFMA(lf.v, af, al);
    }

    // g = (h@A) * (x@B) -> LDS, hi/lo bf16, A-fragment layout
#pragma unroll
    for (int rg = 0; rg < 4; ++rg) {
      int s = kq * 4 + rg;
      float gval = (ah[rg] + al[rg]) * bp[rg];
      unsigned short ghi = f2bf(gval);
      unsigned short glo = f2bf(gval - bf2f(ghi));
      int base = (s * 64 + w * 16 + fr) * 2;
      int sw = (s & 7) << 4;
      *(unsigned short*)((char*)g2 + (base ^ sw)) = ghi;
      *(unsigned short*)((char*)g2 + ((base + 2048) ^ sw)) = glo;
    }
    __syncthreads();

    // cp: z += g @ C_slice^T  (K = 64, 2 k-steps, hi/lo)
#pragma unroll
    for (int kt2 = 0; kt2 < 2; ++kt2) {
      int k = kt2 * 32 + kq * 8;
      int gsw = (fr & 7) << 4;
      short8 gh = *(const short8*)((const char*)g2 + (((fr * 64 + k) * 2) ^ gsw));
      short8 gl = *(const short8*)((const char*)g2 + (((fr * 64 + k) * 2 + 2048) ^ gsw));
      short8 cf = *(const short8*)((const char*)Cs +
                                   ((((w * 16 + fr) * 64 + k) * 2) ^ gsw));
      zh = MFMA(gh, cf, zh);
      zl = MFMA(gl, cf, zl);
    }

    // epilogue: h_new = tanh(z + ucz); store hseq + H2[nxt] (hi/lo, agent scope)
    unsigned short* Hn = H2 + nxt * 32768;
#pragma unroll
    for (int rg = 0; rg < 4; ++rg) {
      int s = kq * 4 + rg;
      float z = zh[rg] + zl[rg] + ucz[rg];
      float h = tanhf(z);
      unsigned short hi = f2bf(h);
      hseq[(size_t)(t * 16 + s) * HID + jg] = hi;
      unsigned short lo = f2bf(h - bf2f(hi));
      __hip_atomic_store(Hn + s * 1024 + jg, hi, __ATOMIC_RELAXED,
                         __HIP_MEMORY_SCOPE_AGENT);
      __hip_atomic_store(Hn + 16384 + s * 1024 + jg, lo, __ATOMIC_RELAXED,
                         __HIP_MEMORY_SCOPE_AGENT);
    }

    // prefetch next step's u_cat terms (independent of H; hides under barrier)
    {
      int tn = (t + 1 < SEQ) ? t + 1 : t;
#pragma unroll
      for (int rg = 0; rg < 4; ++rg) {
        int s = kq * 4 + rg;
        const float* ur = u_cat + (size_t)(tn * 16 + s) * N1;
        ucz[rg] = ur[jg];
        bp[rg] = ur[HID + w * 16 + fr];
      }
    }

    // single grid barrier, fence-free: __syncthreads drains all waves' stores
    // to the coherence point; relaxed agent atomics bypass L2 -> no cacheops.
    __syncthreads();
    if (tid == 0) {
      __hip_atomic_fetch_add(bars, 1u, __ATOMIC_RELAXED, __HIP_MEMORY_SCOPE_AGENT);
      unsigned int tg = (unsigned int)(t + 1) * 16u;
      while (__hip_atomic_load(bars, __ATOMIC_RELAXED, __HIP_MEMORY_SCOPE_AGENT) < tg)
        __builtin_amdgcn_s_sleep(1);
    }
    __syncthreads();
  }
}

// ---------------------------------------------------------------------------
extern "C" void kernel_launch(void* const* d_in, const int* in_sizes, int n_in,
                              void* d_out, int out_size, void* d_ws, size_t ws_size,
                              hipStream_t stream) {
  const int*   inp  = (const int*)d_in[0];
  const float* emb  = (const float*)d_in[1];   // [32000][512]
  const float* Amat = (const float*)d_in[2];   // [1024][64]
  const float* Bmat = (const float*)d_in[3];   // [512][64]
  const float* Cmat = (const float*)d_in[4];   // [1024][64]
  const float* Umat = (const float*)d_in[5];   // [512][1024]
  const float* Vmat = (const float*)d_in[6];   // [1024][1024]
  const float* dvec = (const float*)d_in[7];   // [1024]
  const float* Wdec = (const float*)d_in[8];   // [1024][32000]
  const float* bdec = (const float*)d_in[9];   // [32000]
  float* out = (float*)d_out;

  char* ws = (char*)d_ws;
  size_t off = 0;
  auto alloc = [&](size_t bytes) -> void* {
    void* pp = ws + off;
    off = (off + bytes + 255) & ~(size_t)255;
    return pp;
  };
  // persistent region
  unsigned short* hseq = (unsigned short*)alloc((size_t)MROWS * HID * 2);   // 8.39 MB
  unsigned short* H2   = (unsigned short*)alloc((size_t)2 * 2 * BATCH * HID * 2); // 128 KB
  unsigned short* ATb  = (unsigned short*)alloc((size_t)RANK * HID * 2);    // 128 KB
  unsigned int* bars   = (unsigned int*)alloc(1024 * 4);
  // union region: {emb_bf16, UBt, u_cat} (phases 1-3) aliased with WdT (4-5)
  size_t union_off = off;
  unsigned short* emb_b = (unsigned short*)alloc((size_t)VOCAB * EMB * 2);  // 32.8 MB
  unsigned short* UBt   = (unsigned short*)alloc((size_t)N1PAD * EMB * 2);  // 1.18 MB
  float* u_cat = (float*)alloc((size_t)MROWS * N1 * 4);                     // 17.8 MB
  unsigned short* WdT = (unsigned short*)(ws + union_off);                  // 65.5 MB alias

  // phase 0: prep + conversions (H2 buf0 = 65536 B = 16384 floats zeroed)
  prep_misc<<<128, 256, 0, stream>>>((float*)H2, bars, UBt + (size_t)N1 * EMB);
  conv_f2b<<<(VOCAB * EMB) / 1024, 256, 0, stream>>>(emb, emb_b);
  // UBt rows 0..1023 = U^T, rows 1024..1087 = B^T, rows 1088..1151 = 0
  transpose_f2b<<<dim3(HID / 32, EMB / 32), 256, 0, stream>>>(Umat, UBt, EMB, HID);
  transpose_f2b<<<dim3(RANK / 32, EMB / 32), 256, 0, stream>>>(
      Bmat, UBt + (size_t)HID * EMB, EMB, RANK);
  // A^T bf16 [64][1024] for the scan's rank projection
  transpose_f2b<<<dim3(RANK / 32, HID / 32), 256, 0, stream>>>(Amat, ATb, HID, RANK);

  // phase 1: u_cat = gather(embedding, inp) @ [U | B] + [d | 0]
  gemm_bt<0><<<9 * (MROWS / 128), 256, 0, stream>>>(emb_b, inp, UBt, dvec, u_cat,
                                                    MROWS, N1, EMB, 9);
  // phase 2: recurrent scan (16 blocks, MFMA, 1 fence-free barrier/step)
  scan_kernel<<<16, 256, 0, stream>>>(u_cat, ATb, Vmat, Cmat, H2, bars, hseq);
  // phase 3: W_dec transpose (aliases dead emb_b/UBt/u_cat region)
  transpose_f2b<<<dim3(VOCAB / 32, HID / 32), 256, 0, stream>>>(Wdec, WdT, HID, VOCAB);
  // phase 4: logits = hseq @ W_dec + b_dec, remapped to [B,S,V]
  gemm_bt<1><<<250 * (MROWS / 128), 256, 0, stream>>>(hseq, nullptr, WdT, bdec, out,
                                                      MROWS, VOCAB, HID, 250);
}